// Round 1
// baseline (466.159 us; speedup 1.0000x reference)
//
#include <hip/hip_runtime.h>
#include <hip/hip_bf16.h>

#define H_DIM  1024
#define RANK_  4
#define BATCH_ 128
#define TSTEPS 256
#define M_DIM  (BATCH_ * TSTEPS)   // 32768

typedef __bf16 bf16x8 __attribute__((ext_vector_type(8)));
typedef float  floatx4 __attribute__((ext_vector_type(4)));
typedef unsigned short ushortx8 __attribute__((ext_vector_type(8)));

// RNE float -> bf16 (branchless; inputs are finite)
__device__ __forceinline__ unsigned short f2bf(float f) {
    unsigned u = __float_as_uint(f);
    u += 0x7FFFu + ((u >> 16) & 1u);
    return (unsigned short)(u >> 16);
}

// ---------------- conversion kernels ----------------

__global__ __launch_bounds__(256) void cvt_x_kernel(const float* __restrict__ x,
                                                    unsigned short* __restrict__ xb) {
    size_t i = ((size_t)blockIdx.x * 256 + threadIdx.x) * 8;
    float4 v0 = *(const float4*)(x + i);
    float4 v1 = *(const float4*)(x + i + 4);
    ushortx8 o;
    o[0] = f2bf(v0.x); o[1] = f2bf(v0.y); o[2] = f2bf(v0.z); o[3] = f2bf(v0.w);
    o[4] = f2bf(v1.x); o[5] = f2bf(v1.y); o[6] = f2bf(v1.z); o[7] = f2bf(v1.w);
    *(ushortx8*)(xb + i) = o;
}

// Bt[n][k] = bf16(B[k][n])
__global__ __launch_bounds__(256) void cvt_bt_kernel(const float* __restrict__ B,
                                                     unsigned short* __restrict__ Bt) {
    __shared__ float tl[32][33];
    int tx = threadIdx.x & 31, ty = threadIdx.x >> 5;   // ty in 0..7
    int k0 = blockIdx.y * 32, n0 = blockIdx.x * 32;
#pragma unroll
    for (int j = 0; j < 4; ++j)
        tl[ty + 8 * j][tx] = B[(size_t)(k0 + ty + 8 * j) * H_DIM + n0 + tx];
    __syncthreads();
#pragma unroll
    for (int j = 0; j < 4; ++j)
        Bt[(size_t)(n0 + ty + 8 * j) * H_DIM + k0 + tx] = f2bf(tl[tx][ty + 8 * j]);
}

// ---------------- bf16 MFMA GEMM: C[M][N] = A[M][K] * Bt[N][K]^T ----------------
// 128x128 tile, 4 waves in 2x2, each wave 64x64 = 4x4 tiles of 16x16x32 MFMA.

#define TM 128
#define TN 128
#define BK 64
#define BKP 72   // +8 bf16 pad: breaks power-of-2 LDS strides, keeps 16B alignment

__global__ __launch_bounds__(256) void gemm_bf16_kernel(const unsigned short* __restrict__ A,
                                                        const unsigned short* __restrict__ Bt,
                                                        float* __restrict__ C) {
    __shared__ unsigned short As[TM * BKP];
    __shared__ unsigned short Bs[TN * BKP];

    const int tid  = threadIdx.x;
    const int lane = tid & 63;
    const int wid  = tid >> 6;
    const int wm = (wid >> 1) * 64, wn = (wid & 1) * 64;
    const int bm = blockIdx.x >> 3, bn = blockIdx.x & 7;   // N/TN = 8
    const int m0 = bm * TM, n0 = bn * TN;

    // staging: thread covers 16B chunk; 8 chunks per 64-col row -> 32 rows/pass, 4 passes
    const int sr = tid >> 3;          // 0..31
    const int sc = (tid & 7) * 8;     // 0..56
    const unsigned short* Ag = A  + (size_t)(m0 + sr) * H_DIM + sc;
    const unsigned short* Bg = Bt + (size_t)(n0 + sr) * H_DIM + sc;

    floatx4 acc[4][4];
#pragma unroll
    for (int i = 0; i < 4; ++i)
#pragma unroll
        for (int j = 0; j < 4; ++j) acc[i][j] = (floatx4){0.f, 0.f, 0.f, 0.f};

    const int fr = lane & 15;
    const int fk = (lane >> 4) * 8;

    for (int kt = 0; kt < H_DIM; kt += BK) {
        ushortx8 ar[4], br[4];
#pragma unroll
        for (int p = 0; p < 4; ++p) {
            ar[p] = *(const ushortx8*)(Ag + (size_t)(32 * p) * H_DIM + kt);
            br[p] = *(const ushortx8*)(Bg + (size_t)(32 * p) * H_DIM + kt);
        }
        __syncthreads();   // previous iter's frag reads done before overwrite
#pragma unroll
        for (int p = 0; p < 4; ++p) {
            *(ushortx8*)(As + (sr + 32 * p) * BKP + sc) = ar[p];
            *(ushortx8*)(Bs + (sr + 32 * p) * BKP + sc) = br[p];
        }
        __syncthreads();
#pragma unroll
        for (int ks = 0; ks < BK; ks += 32) {
            bf16x8 af[4], bfr[4];
#pragma unroll
            for (int i = 0; i < 4; ++i)
                af[i] = *(const bf16x8*)(As + (wm + i * 16 + fr) * BKP + ks + fk);
#pragma unroll
            for (int j = 0; j < 4; ++j)
                bfr[j] = *(const bf16x8*)(Bs + (wn + j * 16 + fr) * BKP + ks + fk);
#pragma unroll
            for (int i = 0; i < 4; ++i)
#pragma unroll
                for (int j = 0; j < 4; ++j)
                    acc[i][j] = __builtin_amdgcn_mfma_f32_16x16x32_bf16(af[i], bfr[j], acc[i][j], 0, 0, 0);
        }
    }

    // epilogue: C/D layout col=lane&15, row=(lane>>4)*4+reg  [m89/m91 verified]
    const int cr = (lane >> 4) * 4;
    const int cc = lane & 15;
#pragma unroll
    for (int i = 0; i < 4; ++i)
#pragma unroll
        for (int j = 0; j < 4; ++j) {
            size_t base = (size_t)(m0 + wm + i * 16 + cr) * H_DIM + (n0 + wn + j * 16 + cc);
#pragma unroll
            for (int r = 0; r < 4; ++r)
                C[base + (size_t)r * H_DIM] = acc[i][j][r];
        }
}

// ---------------- fp32 fallback GEMM (only if ws too small) ----------------
__global__ __launch_bounds__(256) void gemm_fp32_fallback(const float* __restrict__ A,
                                                          const float* __restrict__ B,
                                                          float* __restrict__ C) {
    __shared__ float As[64][20];
    __shared__ float Bs[16][68];
    const int tid = threadIdx.x;
    const int bm = blockIdx.x >> 4, bn = blockIdx.x & 15;  // N/64 = 16
    const int m0 = bm * 64, n0 = bn * 64;
    const int tx = (tid & 15) * 4, ty = (tid >> 4) * 4;
    float acc[4][4];
#pragma unroll
    for (int i = 0; i < 4; ++i)
#pragma unroll
        for (int j = 0; j < 4; ++j) acc[i][j] = 0.f;

    for (int kk = 0; kk < H_DIM; kk += 16) {
        float4 av = *(const float4*)(A + (size_t)(m0 + (tid >> 2)) * H_DIM + kk + (tid & 3) * 4);
        float4 bv = *(const float4*)(B + (size_t)(kk + (tid >> 4)) * H_DIM + n0 + (tid & 15) * 4);
        __syncthreads();
        *(float4*)&As[tid >> 2][(tid & 3) * 4] = av;
        *(float4*)&Bs[tid >> 4][(tid & 15) * 4] = bv;
        __syncthreads();
#pragma unroll
        for (int k = 0; k < 16; ++k) {
            float a_[4], b_[4];
#pragma unroll
            for (int i = 0; i < 4; ++i) a_[i] = As[ty + i][k];
#pragma unroll
            for (int j = 0; j < 4; ++j) b_[j] = Bs[k][tx + j];
#pragma unroll
            for (int i = 0; i < 4; ++i)
#pragma unroll
                for (int j = 0; j < 4; ++j) acc[i][j] += a_[i] * b_[j];
        }
    }
#pragma unroll
    for (int i = 0; i < 4; ++i)
#pragma unroll
        for (int j = 0; j < 4; ++j)
            C[(size_t)(m0 + ty + i) * H_DIM + n0 + tx + j] = acc[i][j];
}

// ---------------- sequential scan (in-place on d_out) ----------------

__device__ __forceinline__ float tanh_fast(float x) {
    float ax = fabsf(x);
    float e  = __expf(-2.0f * ax);
    float t  = (1.0f - e) * __builtin_amdgcn_rcpf(1.0f + e);
    return copysignf(t, x);
}

__global__ __launch_bounds__(256) void scan_kernel(const float* __restrict__ h0,
                                                   const float* __restrict__ d,
                                                   const float* __restrict__ Lm,
                                                   const float* __restrict__ Rm,
                                                   float* __restrict__ io) {
    const int b = blockIdx.x, tid = threadIdx.x;
    const int lane = tid & 63, wv = tid >> 6;
    const int e = tid * 4;

    float4 dv4 = *(const float4*)(d + e);
    float dd[4] = {dv4.x, dv4.y, dv4.z, dv4.w};
    float4 hv4 = *(const float4*)(h0 + (size_t)b * H_DIM + e);
    float h[4] = {hv4.x, hv4.y, hv4.z, hv4.w};

    float Lv[4][4], Rv[4][4];
#pragma unroll
    for (int i = 0; i < 4; ++i) {
        float4 t = *(const float4*)(Lm + (size_t)(e + i) * RANK_);   // L[h][j], row = 4 floats
        Lv[i][0] = t.x; Lv[i][1] = t.y; Lv[i][2] = t.z; Lv[i][3] = t.w;
    }
#pragma unroll
    for (int j = 0; j < 4; ++j) {
        float4 t = *(const float4*)(Rm + (size_t)j * H_DIM + e);     // R[j][h]
        Rv[j][0] = t.x; Rv[j][1] = t.y; Rv[j][2] = t.z; Rv[j][3] = t.w;
    }

    float* iob = io + (size_t)b * TSTEPS * H_DIM + e;
    __shared__ float red[2][4][4];

    float4 u0 = *(const float4*)(iob);
    float4 u1 = *(const float4*)(iob + H_DIM);

    for (int t = 0; t < TSTEPS; ++t) {
        float4 u = u0;
        u0 = u1;
        if (t + 2 < TSTEPS) u1 = *(const float4*)(iob + (size_t)(t + 2) * H_DIM);

        float pr[4];
#pragma unroll
        for (int j = 0; j < 4; ++j)
            pr[j] = Rv[j][0] * h[0] + Rv[j][1] * h[1] + Rv[j][2] * h[2] + Rv[j][3] * h[3];
#pragma unroll
        for (int s = 32; s > 0; s >>= 1) {
#pragma unroll
            for (int j = 0; j < 4; ++j) pr[j] += __shfl_xor(pr[j], s, 64);
        }
        if (lane == 0) {
            float4 w = {pr[0], pr[1], pr[2], pr[3]};
            *(float4*)&red[t & 1][wv][0] = w;
        }
        __syncthreads();
        float4 r0 = *(const float4*)&red[t & 1][0][0];
        float4 r1 = *(const float4*)&red[t & 1][1][0];
        float4 r2 = *(const float4*)&red[t & 1][2][0];
        float4 r3 = *(const float4*)&red[t & 1][3][0];
        float r[4] = {r0.x + r1.x + r2.x + r3.x, r0.y + r1.y + r2.y + r3.y,
                      r0.z + r1.z + r2.z + r3.z, r0.w + r1.w + r2.w + r3.w};

        float uu[4] = {u.x, u.y, u.z, u.w};
#pragma unroll
        for (int i = 0; i < 4; ++i) {
            float a = dd[i] * h[i] + uu[i];
            a += Lv[i][0] * r[0] + Lv[i][1] * r[1] + Lv[i][2] * r[2] + Lv[i][3] * r[3];
            h[i] = tanh_fast(a);
        }
        float4 o = {h[0], h[1], h[2], h[3]};
        *(float4*)(iob + (size_t)t * H_DIM) = o;
    }
}

// ---------------- launch ----------------

extern "C" void kernel_launch(void* const* d_in, const int* in_sizes, int n_in,
                              void* d_out, int out_size, void* d_ws, size_t ws_size,
                              hipStream_t stream) {
    const float* x  = (const float*)d_in[0];
    const float* h0 = (const float*)d_in[1];
    const float* dd = (const float*)d_in[2];
    const float* L  = (const float*)d_in[3];
    const float* R  = (const float*)d_in[4];
    const float* B  = (const float*)d_in[5];
    float* out = (float*)d_out;

    const size_t need = (size_t)M_DIM * H_DIM * sizeof(unsigned short)
                      + (size_t)H_DIM * H_DIM * sizeof(unsigned short);
    if (ws_size >= need) {
        unsigned short* xb = (unsigned short*)d_ws;
        unsigned short* Bt = xb + (size_t)M_DIM * H_DIM;
        cvt_x_kernel<<<(M_DIM * H_DIM) / (256 * 8), 256, 0, stream>>>(x, xb);
        cvt_bt_kernel<<<dim3(32, 32), 256, 0, stream>>>(B, Bt);
        gemm_bf16_kernel<<<(M_DIM / TM) * (H_DIM / TN), 256, 0, stream>>>(xb, Bt, out);
    } else {
        gemm_fp32_fallback<<<(M_DIM / 64) * (H_DIM / 64), 256, 0, stream>>>(x, B, out);
    }
    scan_kernel<<<BATCH_, 256, 0, stream>>>(h0, dd, L, R, out);
}

// Round 2
// 461.925 us; speedup vs baseline: 1.0092x; 1.0092x over previous
//
#include <hip/hip_runtime.h>
#include <hip/hip_bf16.h>

#define H_DIM  1024
#define RANK_  4
#define BATCH_ 128
#define TSTEPS 256
#define M_DIM  (BATCH_ * TSTEPS)   // 32768

typedef __bf16 bf16x8 __attribute__((ext_vector_type(8)));
typedef float  floatx4 __attribute__((ext_vector_type(4)));
typedef unsigned short ushortx8 __attribute__((ext_vector_type(8)));

// RNE float -> bf16 (branchless; inputs are finite)
__device__ __forceinline__ unsigned short f2bf(float f) {
    unsigned u = __float_as_uint(f);
    u += 0x7FFFu + ((u >> 16) & 1u);
    return (unsigned short)(u >> 16);
}

// ---------------- conversion kernels ----------------

__global__ __launch_bounds__(256) void cvt_x_kernel(const float* __restrict__ x,
                                                    unsigned short* __restrict__ xb) {
    size_t i = ((size_t)blockIdx.x * 256 + threadIdx.x) * 8;
    float4 v0 = *(const float4*)(x + i);
    float4 v1 = *(const float4*)(x + i + 4);
    ushortx8 o;
    o[0] = f2bf(v0.x); o[1] = f2bf(v0.y); o[2] = f2bf(v0.z); o[3] = f2bf(v0.w);
    o[4] = f2bf(v1.x); o[5] = f2bf(v1.y); o[6] = f2bf(v1.z); o[7] = f2bf(v1.w);
    *(ushortx8*)(xb + i) = o;
}

// Bt[n][k] = bf16(B[k][n])
__global__ __launch_bounds__(256) void cvt_bt_kernel(const float* __restrict__ B,
                                                     unsigned short* __restrict__ Bt) {
    __shared__ float tl[32][33];
    int tx = threadIdx.x & 31, ty = threadIdx.x >> 5;   // ty in 0..7
    int k0 = blockIdx.y * 32, n0 = blockIdx.x * 32;
#pragma unroll
    for (int j = 0; j < 4; ++j)
        tl[ty + 8 * j][tx] = B[(size_t)(k0 + ty + 8 * j) * H_DIM + n0 + tx];
    __syncthreads();
#pragma unroll
    for (int j = 0; j < 4; ++j)
        Bt[(size_t)(n0 + ty + 8 * j) * H_DIM + k0 + tx] = f2bf(tl[tx][ty + 8 * j]);
}

// ---------------- bf16 MFMA GEMM: C[M][N] = A[M][K] * Bt[N][K]^T ----------------
// 128x128 tile, BK=64, 4 waves in 2x2, each wave 64x64 = 4x4 tiles of 16x16x32.
// LDS holds 16x32 operand blocks in FRAGMENT-LANE ORDER: lane l's 16B at
// blockbase + l*16 == A[row = l&15][k = (l>>4)*8 .. +8]. This satisfies
// global_load_lds's wave-uniform-base + lane*16 constraint AND makes the
// fragment ds_read_b128 (addr = base + lane*16) bank-conflict-free.

#define TM 128
#define TN 128
#define BK 64

__global__ __launch_bounds__(256) void gemm_bf16_kernel(const unsigned short* __restrict__ A,
                                                        const unsigned short* __restrict__ Bt,
                                                        float* __restrict__ C) {
    __shared__ unsigned short As[TM * BK];   // 16 blocks x 512 shorts (16KB)
    __shared__ unsigned short Bs[TN * BK];

    const int tid  = threadIdx.x;
    const int lane = tid & 63;
    const int wid  = tid >> 6;
    const int wm = (wid >> 1) * 64, wn = (wid & 1) * 64;
    const int bm = blockIdx.x >> 3, bn = blockIdx.x & 7;   // N/TN = 8
    const int m0 = bm * TM, n0 = bn * TN;

    const int lr = lane & 15;          // row within a 16-row block
    const int lk = (lane >> 4) * 8;    // k offset within a 32-k block

    // each wave stages 4 A-blocks and 4 B-blocks per BK step
    const unsigned short* ag[4];
    const unsigned short* bg[4];
    unsigned short* asl[4];
    unsigned short* bsl[4];
#pragma unroll
    for (int p = 0; p < 4; ++p) {
        const int ab = wid * 4 + p;
        const int rb = ab >> 1, kb = ab & 1;
        ag[p]  = A  + (size_t)(m0 + rb * 16 + lr) * H_DIM + kb * 32 + lk;
        bg[p]  = Bt + (size_t)(n0 + rb * 16 + lr) * H_DIM + kb * 32 + lk;
        asl[p] = As + ab * 512;
        bsl[p] = Bs + ab * 512;
    }

    floatx4 acc[4][4];
#pragma unroll
    for (int i = 0; i < 4; ++i)
#pragma unroll
        for (int j = 0; j < 4; ++j) acc[i][j] = (floatx4){0.f, 0.f, 0.f, 0.f};

    for (int kt = 0; kt < H_DIM; kt += BK) {
        __syncthreads();   // previous iter's fragment reads done before overwrite
#pragma unroll
        for (int p = 0; p < 4; ++p) {
            __builtin_amdgcn_global_load_lds(
                (const __attribute__((address_space(1))) void*)(ag[p] + kt),
                (__attribute__((address_space(3))) void*)asl[p], 16, 0, 0);
            __builtin_amdgcn_global_load_lds(
                (const __attribute__((address_space(1))) void*)(bg[p] + kt),
                (__attribute__((address_space(3))) void*)bsl[p], 16, 0, 0);
        }
        __syncthreads();   // compiler drains vmcnt(0) here -> LDS data visible
#pragma unroll
        for (int kb = 0; kb < 2; ++kb) {
            bf16x8 af[4], bfv[4];
#pragma unroll
            for (int i = 0; i < 4; ++i) {
                const int rbA = (wm >> 4) + i;
                af[i] = *(const bf16x8*)(As + ((rbA * 2 + kb) << 9) + (lane << 3));
            }
#pragma unroll
            for (int j = 0; j < 4; ++j) {
                const int rbB = (wn >> 4) + j;
                bfv[j] = *(const bf16x8*)(Bs + ((rbB * 2 + kb) << 9) + (lane << 3));
            }
#pragma unroll
            for (int i = 0; i < 4; ++i)
#pragma unroll
                for (int j = 0; j < 4; ++j)
                    acc[i][j] = __builtin_amdgcn_mfma_f32_16x16x32_bf16(af[i], bfv[j], acc[i][j], 0, 0, 0);
        }
    }

    // epilogue: C/D layout col=lane&15, row=(lane>>4)*4+reg  [m89/m91 verified]
    const int cr = (lane >> 4) * 4;
    const int cc = lane & 15;
#pragma unroll
    for (int i = 0; i < 4; ++i)
#pragma unroll
        for (int j = 0; j < 4; ++j) {
            size_t base = (size_t)(m0 + wm + i * 16 + cr) * H_DIM + (n0 + wn + j * 16 + cc);
#pragma unroll
            for (int r = 0; r < 4; ++r)
                C[base + (size_t)r * H_DIM] = acc[i][j][r];
        }
}

// ---------------- fp32 fallback GEMM (only if ws too small) ----------------
__global__ __launch_bounds__(256) void gemm_fp32_fallback(const float* __restrict__ A,
                                                          const float* __restrict__ B,
                                                          float* __restrict__ C) {
    __shared__ float As[64][20];
    __shared__ float Bs[16][68];
    const int tid = threadIdx.x;
    const int bm = blockIdx.x >> 4, bn = blockIdx.x & 15;
    const int m0 = bm * 64, n0 = bn * 64;
    const int tx = (tid & 15) * 4, ty = (tid >> 4) * 4;
    float acc[4][4];
#pragma unroll
    for (int i = 0; i < 4; ++i)
#pragma unroll
        for (int j = 0; j < 4; ++j) acc[i][j] = 0.f;

    for (int kk = 0; kk < H_DIM; kk += 16) {
        float4 av = *(const float4*)(A + (size_t)(m0 + (tid >> 2)) * H_DIM + kk + (tid & 3) * 4);
        float4 bv = *(const float4*)(B + (size_t)(kk + (tid >> 4)) * H_DIM + n0 + (tid & 15) * 4);
        __syncthreads();
        *(float4*)&As[tid >> 2][(tid & 3) * 4] = av;
        *(float4*)&Bs[tid >> 4][(tid & 15) * 4] = bv;
        __syncthreads();
#pragma unroll
        for (int k = 0; k < 16; ++k) {
            float a_[4], b_[4];
#pragma unroll
            for (int i = 0; i < 4; ++i) a_[i] = As[ty + i][k];
#pragma unroll
            for (int j = 0; j < 4; ++j) b_[j] = Bs[k][tx + j];
#pragma unroll
            for (int i = 0; i < 4; ++i)
#pragma unroll
                for (int j = 0; j < 4; ++j) acc[i][j] += a_[i] * b_[j];
        }
    }
#pragma unroll
    for (int i = 0; i < 4; ++i)
#pragma unroll
        for (int j = 0; j < 4; ++j)
            C[(size_t)(m0 + ty + i) * H_DIM + n0 + tx + j] = acc[i][j];
}

// ---------------- sequential scan (in-place on d_out) ----------------

__device__ __forceinline__ float tanh_fast(float x) {
    float ax = fabsf(x);
    float e  = __expf(-2.0f * ax);
    float t  = (1.0f - e) * __builtin_amdgcn_rcpf(1.0f + e);
    return copysignf(t, x);
}

// LDS-only barrier: drains lgkmcnt but NOT vmcnt, so global prefetch loads
// and h-stores stay in flight across the barrier (unlike __syncthreads,
// which emits s_waitcnt vmcnt(0) and exposes full memory latency per step).
__device__ __forceinline__ void barrier_lds_only() {
    asm volatile("s_waitcnt lgkmcnt(0)\n\ts_barrier" ::: "memory");
}

// DPP wave64 sum: full sum lands in lane 63 (VALU-rate, no LDS/ds_permute).
template <int CTRL, int RMASK>
__device__ __forceinline__ float dpp_add(float x) {
    int v = __builtin_amdgcn_update_dpp(0, __float_as_int(x), CTRL, RMASK, 0xf, true);
    return x + __int_as_float(v);
}
__device__ __forceinline__ float wave_sum64(float x) {
    x = dpp_add<0x111, 0xf>(x);  // row_shr:1
    x = dpp_add<0x112, 0xf>(x);  // row_shr:2
    x = dpp_add<0x114, 0xf>(x);  // row_shr:4
    x = dpp_add<0x118, 0xf>(x);  // row_shr:8  -> lane15 of each row = row sum
    x = dpp_add<0x142, 0xa>(x);  // row_bcast15 -> rows 1,3
    x = dpp_add<0x143, 0xc>(x);  // row_bcast31 -> rows 2,3; lane 63 = total
    return x;
}

__global__ __launch_bounds__(256) void scan_kernel(const float* __restrict__ h0,
                                                   const float* __restrict__ d,
                                                   const float* __restrict__ Lm,
                                                   const float* __restrict__ Rm,
                                                   float* __restrict__ io) {
    const int b = blockIdx.x, tid = threadIdx.x;
    const int lane = tid & 63, wv = tid >> 6;
    const int e = tid * 4;

    float4 dv4 = *(const float4*)(d + e);
    float dd[4] = {dv4.x, dv4.y, dv4.z, dv4.w};
    float4 hv4 = *(const float4*)(h0 + (size_t)b * H_DIM + e);
    float h[4] = {hv4.x, hv4.y, hv4.z, hv4.w};

    float Lv[4][4], Rv[4][4];
#pragma unroll
    for (int i = 0; i < 4; ++i) {
        float4 t = *(const float4*)(Lm + (size_t)(e + i) * RANK_);   // L[h][j]
        Lv[i][0] = t.x; Lv[i][1] = t.y; Lv[i][2] = t.z; Lv[i][3] = t.w;
    }
#pragma unroll
    for (int j = 0; j < 4; ++j) {
        float4 t = *(const float4*)(Rm + (size_t)j * H_DIM + e);     // R[j][h]
        Rv[j][0] = t.x; Rv[j][1] = t.y; Rv[j][2] = t.z; Rv[j][3] = t.w;
    }

    float* iob = io + (size_t)b * TSTEPS * H_DIM + e;
    __shared__ float red[2][4][4];   // double-buffered: 1 barrier/step is sound

    // prefetch distance 4, circular buffer, loop unrolled by 4 (static index)
    float4 u[4];
#pragma unroll
    for (int s = 0; s < 4; ++s) u[s] = *(const float4*)(iob + (size_t)s * H_DIM);

    for (int t = 0; t < TSTEPS; t += 4) {
#pragma unroll
        for (int s = 0; s < 4; ++s) {
            const int tt = t + s;
            float pr[4];
#pragma unroll
            for (int j = 0; j < 4; ++j)
                pr[j] = Rv[j][0] * h[0] + Rv[j][1] * h[1] + Rv[j][2] * h[2] + Rv[j][3] * h[3];
#pragma unroll
            for (int j = 0; j < 4; ++j) pr[j] = wave_sum64(pr[j]);
            if (lane == 63) {
                float4 w; w.x = pr[0]; w.y = pr[1]; w.z = pr[2]; w.w = pr[3];
                *(float4*)&red[s & 1][wv][0] = w;
            }
            barrier_lds_only();
            float4 r0 = *(const float4*)&red[s & 1][0][0];
            float4 r1 = *(const float4*)&red[s & 1][1][0];
            float4 r2 = *(const float4*)&red[s & 1][2][0];
            float4 r3 = *(const float4*)&red[s & 1][3][0];
            float r[4] = {r0.x + r1.x + r2.x + r3.x, r0.y + r1.y + r2.y + r3.y,
                          r0.z + r1.z + r2.z + r3.z, r0.w + r1.w + r2.w + r3.w};

            float uu[4] = {u[s].x, u[s].y, u[s].z, u[s].w};
#pragma unroll
            for (int i = 0; i < 4; ++i) {
                float a = fmaf(dd[i], h[i], uu[i]);
                a += Lv[i][0] * r[0] + Lv[i][1] * r[1] + Lv[i][2] * r[2] + Lv[i][3] * r[3];
                h[i] = tanh_fast(a);
            }
            float4 o; o.x = h[0]; o.y = h[1]; o.z = h[2]; o.w = h[3];
            *(float4*)(iob + (size_t)tt * H_DIM) = o;
            if (tt + 4 < TSTEPS) u[s] = *(const float4*)(iob + (size_t)(tt + 4) * H_DIM);
        }
    }
}

// ---------------- launch ----------------

extern "C" void kernel_launch(void* const* d_in, const int* in_sizes, int n_in,
                              void* d_out, int out_size, void* d_ws, size_t ws_size,
                              hipStream_t stream) {
    const float* x  = (const float*)d_in[0];
    const float* h0 = (const float*)d_in[1];
    const float* dd = (const float*)d_in[2];
    const float* L  = (const float*)d_in[3];
    const float* R  = (const float*)d_in[4];
    const float* B  = (const float*)d_in[5];
    float* out = (float*)d_out;

    const size_t need = (size_t)M_DIM * H_DIM * sizeof(unsigned short)
                      + (size_t)H_DIM * H_DIM * sizeof(unsigned short);
    if (ws_size >= need) {
        unsigned short* xb = (unsigned short*)d_ws;
        unsigned short* Bt = xb + (size_t)M_DIM * H_DIM;
        cvt_x_kernel<<<(M_DIM * H_DIM) / (256 * 8), 256, 0, stream>>>(x, xb);
        cvt_bt_kernel<<<dim3(32, 32), 256, 0, stream>>>(B, Bt);
        gemm_bf16_kernel<<<(M_DIM / TM) * (H_DIM / TN), 256, 0, stream>>>(xb, Bt, out);
    } else {
        gemm_fp32_fallback<<<(M_DIM / 64) * (H_DIM / 64), 256, 0, stream>>>(x, B, out);
    }
    scan_kernel<<<BATCH_, 256, 0, stream>>>(h0, dd, L, R, out);
}